// Round 1
// baseline (4056.949 us; speedup 1.0000x reference)
//
#include <hip/hip_runtime.h>
#include <stdint.h>
#include <stddef.h>

// ---------------- problem constants ----------------
#define BATCH 8
#define NPT   2048
#define NB    (BATCH*NPT)            // 16384
#define CAP   128                    // max sparse entries per row/col (lambda<=~63, 8-sigma safe)
#define ITERS 100
#define TPB   1024
#define NWAVE (TPB/64)
#define ROWS_PER_BLK 64              // NPT / 32 blocks-per-batch
#define C50      1.9287498479639178e-22f   // expf(-50.f), matches clamp value exactly
#define MUV      (1.0f/2048.0f)
#define EPS_DIVF 1e-8f

// ---------------- workspace layout (bytes) ----------------
#define OFF_ROWCNT 0u
#define OFF_COLCNT ((size_t)NB*4)                    // 65536
#define OFF_BAR    ((size_t)NB*8)                    // 131072 (8 batches * 128B)
#define OFF_SPTS   ((size_t)NB*8 + 4096)             // 135168, 16B aligned
#define OFF_TPTS   (OFF_SPTS + (size_t)NB*16)
#define OFF_U      (OFF_TPTS + (size_t)NB*16)
#define OFF_V      (OFF_U + (size_t)NB*4)
#define OFF_ROWM   (OFF_V + (size_t)NB*4)
#define OFF_COLM   (OFF_ROWM + (size_t)NB*CAP*2)
// total ~8.8 MB

__device__ __forceinline__ void batch_barrier(uint32_t* bcnt, uint32_t* bepo, int nblk)
{
    __syncthreads();
    if (threadIdx.x == 0) {
        __threadfence();  // release: flush block's writes toward device-coherent point
        uint32_t e = __hip_atomic_load(bepo, __ATOMIC_RELAXED, __HIP_MEMORY_SCOPE_AGENT);
        uint32_t a = __hip_atomic_fetch_add(bcnt, 1u, __ATOMIC_ACQ_REL, __HIP_MEMORY_SCOPE_AGENT) + 1u;
        if (a == (uint32_t)nblk) {
            __hip_atomic_store(bcnt, 0u, __ATOMIC_RELAXED, __HIP_MEMORY_SCOPE_AGENT);
            __hip_atomic_fetch_add(bepo, 1u, __ATOMIC_RELEASE, __HIP_MEMORY_SCOPE_AGENT);
        } else {
            while (__hip_atomic_load(bepo, __ATOMIC_RELAXED, __HIP_MEMORY_SCOPE_AGENT) == e) {
                __builtin_amdgcn_s_sleep(1);
            }
        }
        __threadfence();  // acquire: invalidate caches so fresh reads follow
    }
    __syncthreads();
}

extern "C" __global__ __launch_bounds__(TPB, 1)
void emd_sinkhorn_56831007261025(const float* __restrict__ src,
                                 const float* __restrict__ tgt,
                                 float* __restrict__ out,
                                 uint8_t* __restrict__ wsb)
{
    __shared__ float4 pts[NPT];   // 32 KB: "other side" cloud for current phase
    __shared__ float  lw[NPT];    //  8 KB: weights (v in u-phase, u in v-phase)
    __shared__ float  red[NWAVE];

    uint32_t* rowcnt = (uint32_t*)(wsb + OFF_ROWCNT);
    uint32_t* colcnt = (uint32_t*)(wsb + OFF_COLCNT);
    float4*   spts   = (float4*)  (wsb + OFF_SPTS);
    float4*   tpts   = (float4*)  (wsb + OFF_TPTS);
    float*    gu     = (float*)   (wsb + OFF_U);
    float*    gv     = (float*)   (wsb + OFF_V);
    uint16_t* rowm   = (uint16_t*)(wsb + OFF_ROWM);
    uint16_t* colm   = (uint16_t*)(wsb + OFF_COLM);

    const int tid  = threadIdx.x;
    const int lane = tid & 63;
    const int wid  = tid >> 6;
    const int b    = blockIdx.x & 7;   // batch: &7 keeps a batch's blocks on one XCD (heuristic)
    const int g    = blockIdx.x >> 3;  // group within batch, 0..31
    const int base = b * NPT;

    uint32_t* bcnt = (uint32_t*)(wsb + OFF_BAR + (size_t)b*128);
    uint32_t* bepo = (uint32_t*)(wsb + OFF_BAR + (size_t)b*128 + 64);

    // ---------------- stage float4 point arrays ----------------
    if (tid < ROWS_PER_BLK) {
        int gi = base + g*ROWS_PER_BLK + tid;
        spts[gi] = make_float4(src[3*gi], src[3*gi+1], src[3*gi+2], 0.0f);
        tpts[gi] = make_float4(tgt[3*gi], tgt[3*gi+1], tgt[3*gi+2], 0.0f);
    }
    batch_barrier(bcnt, bepo, 32);

    // ---------------- build sparse lists (d^2 < 0.25) ----------------
    for (int i = tid; i < NPT; i += TPB) pts[i] = tpts[base + i];
    __syncthreads();
    for (int r = 0; r < 4; ++r) {
        int n  = g*ROWS_PER_BLK + wid*4 + r;
        int gi = base + n;
        float4 sp = spts[gi];
        uint32_t cnt = 0;
        for (int mb = 0; mb < NPT; mb += 64) {
            int m = mb + lane;
            float4 tp = pts[m];
            float dx = sp.x - tp.x, dy = sp.y - tp.y, dz = sp.z - tp.z;
            float d2 = dx*dx + dy*dy + dz*dz;
            bool p = d2 < 0.25f;
            uint64_t mask = __ballot(p);
            uint32_t ofs = cnt + (uint32_t)__popcll(mask & ((1ull << lane) - 1ull));
            if (p && ofs < CAP) {
                rowm[(size_t)gi*CAP + ofs] = (uint16_t)m;
                uint32_t j = atomicAdd(&colcnt[base + m], 1u);
                if (j < CAP) colm[(size_t)(base + m)*CAP + j] = (uint16_t)n;
            }
            cnt += (uint32_t)__popcll(mask);
        }
        if (lane == 0) rowcnt[gi] = (cnt < CAP) ? cnt : CAP;
    }
    batch_barrier(bcnt, bepo, 32);

    // ---------------- 100 Sinkhorn iterations (200 half-phases) ----------------
    for (int ph = 0; ph < 2*ITERS; ++ph) {
        const bool up = (ph & 1) == 0;                    // u-phase?
        const float4*   cloud = up ? tpts : spts;         // varying side -> LDS
        const float4*   mine  = up ? spts : tpts;         // my row/col's own point
        const uint32_t* cnts  = up ? rowcnt : colcnt;
        const uint16_t* lists = up ? rowm   : colm;
        const float*    win   = up ? gv     : gu;
        float*          wout  = up ? gu     : gv;

        // load cloud + weights to LDS, block-reduce sum of weights
        float s = 0.0f;
        for (int i = tid; i < NPT; i += TPB) {
            pts[i] = cloud[base + i];
            float w = (ph == 0) ? 1.0f : win[base + i];   // v0 = ones
            lw[i] = w;
            s += w;
        }
        #pragma unroll
        for (int o = 32; o > 0; o >>= 1) s += __shfl_down(s, o, 64);
        if (lane == 0) red[wid] = s;
        __syncthreads();
        float Sw = 0.0f;
        #pragma unroll
        for (int w2 = 0; w2 < NWAVE; ++w2) Sw += red[w2];

        // one wave per row/col, 4 per wave
        for (int r = 0; r < 4; ++r) {
            int gi = base + g*ROWS_PER_BLK + wid*4 + r;
            float4 sp = mine[gi];
            uint32_t cnt = cnts[gi]; if (cnt > CAP) cnt = CAP;
            float acc = 0.0f;
            for (uint32_t j = lane; j < cnt; j += 64) {
                int m = lists[(size_t)gi*CAP + j];
                float4 tp = pts[m];
                float dx = sp.x - tp.x, dy = sp.y - tp.y, dz = sp.z - tp.z;
                float d = sqrtf(dx*dx + dy*dy + dz*dz);
                float K = expf(-fminf(d*100.0f, 50.0f));
                acc = fmaf(K - C50, lw[m], acc);          // subtract background exactly
            }
            #pragma unroll
            for (int o = 32; o > 0; o >>= 1) acc += __shfl_down(acc, o, 64);
            if (lane == 0) {
                float Kv  = fmaf(C50, Sw, acc);           // + exp(-50)*sum(w)
                float val = MUV / fmaxf(Kv, EPS_DIVF);
                __hip_atomic_store(&wout[gi], val, __ATOMIC_RELAXED, __HIP_MEMORY_SCOPE_AGENT);
            }
        }
        batch_barrier(bcnt, bepo, 32);
    }

    // ---------------- EMD epilogue: sum u[n]*K*v[m]*d (dense, one pass) ----------------
    for (int i = tid; i < NPT; i += TPB) {
        pts[i] = tpts[base + i];
        lw[i]  = gv[base + i];
    }
    __syncthreads();
    float wacc = 0.0f;
    for (int r = 0; r < 4; ++r) {
        int gi = base + g*ROWS_PER_BLK + wid*4 + r;
        float4 sp = spts[gi];
        float uval = gu[gi];
        float racc = 0.0f;
        for (int mb = 0; mb < NPT; mb += 64) {
            int m = mb + lane;
            float4 tp = pts[m];
            float dx = sp.x - tp.x, dy = sp.y - tp.y, dz = sp.z - tp.z;
            float d = sqrtf(dx*dx + dy*dy + dz*dz);
            float K = fmaxf(expf(-d*100.0f), C50);        // == exp(-min(100d,50))
            racc = fmaf(K*d, lw[m], racc);
        }
        #pragma unroll
        for (int o = 32; o > 0; o >>= 1) racc += __shfl_down(racc, o, 64);
        if (lane == 0) wacc = fmaf(uval, racc, wacc);
    }
    if (lane == 0) red[wid] = wacc;
    __syncthreads();
    if (tid == 0) {
        float t = 0.0f;
        #pragma unroll
        for (int w2 = 0; w2 < NWAVE; ++w2) t += red[w2];
        atomicAdd(out, t * 0.125f);                        // mean over 8 batches
    }
}

extern "C" void kernel_launch(void* const* d_in, const int* in_sizes, int n_in,
                              void* d_out, int out_size, void* d_ws, size_t ws_size,
                              hipStream_t stream)
{
    const float* src = (const float*)d_in[0];
    const float* tgt = (const float*)d_in[1];
    float* out = (float*)d_out;
    uint8_t* ws = (uint8_t*)d_ws;

    // zero: output accumulator, colcnt (atomic append counters), barrier state
    hipMemsetAsync(out, 0, sizeof(float), stream);
    hipMemsetAsync(ws + OFF_COLCNT, 0, (size_t)NB*4 + 4096, stream);

    void* args[] = { (void*)&src, (void*)&tgt, (void*)&out, (void*)&ws };
    hipLaunchCooperativeKernel((const void*)emd_sinkhorn_56831007261025,
                               dim3(256, 1, 1), dim3(TPB, 1, 1),
                               args, 0, stream);
}

// Round 2
// 3501.187 us; speedup vs baseline: 1.1587x; 1.1587x over previous
//
#include <hip/hip_runtime.h>
#include <stdint.h>
#include <stddef.h>

// ---------------- problem constants ----------------
#define BATCH 8
#define NPT   2048
#define NB    (BATCH*NPT)            // 16384
#define CAP   128                    // max sparse entries per row/col (lambda<=~68, ~7-sigma safe)
#define ITERS 100
#define TPB   1024
#define NWAVE (TPB/64)
#define C50      1.9287498479639178e-22f   // expf(-50.f) == clamp floor of K
#define MUV      (1.0f/2048.0f)
#define EPS_DIVF 1e-8f

// ---------------- workspace layout (bytes), all 16B-aligned ----------------
#define OFF_RCNT 0u
#define OFF_CCNT ((size_t)NB*4)                       // 64 KB
#define OFF_SPTS ((size_t)NB*8)                       // 128 KB
#define OFF_TPTS (OFF_SPTS + (size_t)NB*16)
#define OFF_U    (OFF_TPTS + (size_t)NB*16)
#define OFF_V    (OFF_U + (size_t)NB*4)
#define OFF_ROWE (OFF_V + (size_t)NB*4)               // NB*CAP*4 = 8 MB
#define OFF_COLE (OFF_ROWE + (size_t)NB*CAP*4)        // 8 MB
// total ~17.5 MB

// Pack (K - C50) with 12-bit mantissa + 11-bit index into one dword.
__device__ __forceinline__ uint32_t pack_entry(float kv, int idx) {
    uint32_t b = __float_as_uint(kv);
    b = (b + 0x400u) & 0xFFFFF800u;       // round-to-nearest on stolen bits
    return b | (uint32_t)idx;             // idx < 2048 fits in 11 bits
}

// ================= kernel 1: build sparse lists (deterministic, no atomics) ==========
extern "C" __global__ __launch_bounds__(TPB, 2)
void emd_build_56831007261025(const float* __restrict__ src,
                              const float* __restrict__ tgt,
                              uint8_t* __restrict__ wsb)
{
    __shared__ float4 opts[NPT];   // 32 KB: the scanned ("other") cloud

    uint32_t* rowcnt = (uint32_t*)(wsb + OFF_RCNT);
    uint32_t* colcnt = (uint32_t*)(wsb + OFF_CCNT);
    float4*   gspts  = (float4*)  (wsb + OFF_SPTS);
    float4*   gtpts  = (float4*)  (wsb + OFF_TPTS);
    uint32_t* rowE   = (uint32_t*)(wsb + OFF_ROWE);
    uint32_t* colE   = (uint32_t*)(wsb + OFF_COLE);

    const int tid  = threadIdx.x;
    const int lane = tid & 63;
    const int wid  = tid >> 6;
    const int b    = blockIdx.x >> 5;    // batch 0..7
    const int g    = blockIdx.x & 31;    // 64-row group within batch
    const size_t base = (size_t)b * NPT;

    // stage float4 copies of my 64 src/tgt points for later kernels
    if (tid < 64) {
        size_t gi = base + g*64 + tid;
        gspts[gi] = make_float4(src[3*gi], src[3*gi+1], src[3*gi+2], 0.0f);
        gtpts[gi] = make_float4(tgt[3*gi], tgt[3*gi+1], tgt[3*gi+2], 0.0f);
    }

    for (int pass = 0; pass < 2; ++pass) {
        const float* mineRaw  = pass ? tgt : src;   // the 64 fixed points
        const float* cloudRaw = pass ? src : tgt;   // the 2048 scanned points
        uint32_t*    E        = pass ? colE : rowE;
        uint32_t*    cnts     = pass ? colcnt : rowcnt;

        __syncthreads();
        for (int i = tid; i < NPT; i += TPB) {
            size_t gi = base + i;
            opts[i] = make_float4(cloudRaw[3*gi], cloudRaw[3*gi+1], cloudRaw[3*gi+2], 0.0f);
        }
        __syncthreads();

        for (int r = 0; r < 4; ++r) {
            int n = g*64 + wid*4 + r;
            size_t gi = base + n;
            float4 sp = make_float4(mineRaw[3*gi], mineRaw[3*gi+1], mineRaw[3*gi+2], 0.0f);
            uint32_t cnt = 0;
            for (int mb = 0; mb < NPT; mb += 64) {
                int m = mb + lane;
                float4 tp = opts[m];
                float dx = sp.x - tp.x, dy = sp.y - tp.y, dz = sp.z - tp.z;
                float d2 = dx*dx + dy*dy + dz*dz;
                bool p = d2 < 0.25f;                      // d < 0.5  <=>  100d < 50
                uint64_t mask = __ballot(p);
                uint32_t ofs = cnt + (uint32_t)__popcll(mask & ((1ull << lane) - 1ull));
                if (p && ofs < CAP) {
                    float d  = sqrtf(d2);
                    float kv = expf(-100.0f * d) - C50;   // strictly > 0 here
                    E[gi*CAP + ofs] = pack_entry(kv, m);
                }
                cnt += (uint32_t)__popcll(mask);
            }
            if (lane == 0) cnts[gi] = (cnt < CAP) ? cnt : CAP;
        }
    }
}

// ================= kernel 2: 100 Sinkhorn iterations, one block per batch ============
extern "C" __global__ __launch_bounds__(TPB, 1)
void emd_iterate_56831007261025(uint8_t* __restrict__ wsb)
{
    __shared__ float    lu[NPT];      // 8 KB
    __shared__ float    lv[NPT];      // 8 KB
    __shared__ uint16_t rc[NPT];      // 4 KB
    __shared__ uint16_t cc[NPT];      // 4 KB
    __shared__ float    red[2][NWAVE];

    const uint32_t* rowcnt = (const uint32_t*)(wsb + OFF_RCNT);
    const uint32_t* colcnt = (const uint32_t*)(wsb + OFF_CCNT);
    float*          gu     = (float*)         (wsb + OFF_U);
    float*          gv     = (float*)         (wsb + OFF_V);

    const int tid  = threadIdx.x;
    const int lane = tid & 63;
    const int wid  = tid >> 6;
    const int b    = blockIdx.x;
    const size_t base = (size_t)b * NPT;

    const uint32_t* rowE = (const uint32_t*)(wsb + OFF_ROWE) + base*CAP;
    const uint32_t* colE = (const uint32_t*)(wsb + OFF_COLE) + base*CAP;

    for (int i = tid; i < NPT; i += TPB) {
        rc[i] = (uint16_t)rowcnt[base + i];
        cc[i] = (uint16_t)colcnt[base + i];
        lv[i] = 1.0f;                                   // v0 = ones
    }
    __syncthreads();

    const int sub = lane >> 2;   // 0..15: row within group of 16
    const int l4  = lane & 3;    // 0..3 : entry stride within row

    for (int ph = 0; ph < 2*ITERS; ++ph) {
        const bool up = (ph & 1) == 0;                  // u-phase reads v, writes u
        const uint32_t* E    = up ? rowE : colE;
        const uint16_t* cnts = up ? rc : cc;
        const float*    win  = up ? lv : lu;
        float*          wout = up ? lu : lv;

        float Sw;
        if (ph == 0) {
            Sw = (float)NPT;                            // sum(v0) = 2048 exactly
        } else {
            float s = 0.0f;
            #pragma unroll
            for (int w = 0; w < NWAVE; ++w) s += red[(ph - 1) & 1][w];
            Sw = s;
        }

        float psum = 0.0f;
        #pragma unroll 2
        for (int rg = 0; rg < 8; ++rg) {
            int row = wid*128 + rg*16 + sub;
            uint32_t cnt = cnts[row];
            const uint32_t* ep = E + (size_t)row * CAP;
            float acc = 0.0f;
            for (uint32_t j = l4; j < cnt; j += 4) {
                uint32_t e = ep[j];
                float kv = __uint_as_float(e & 0xFFFFF800u);
                acc = fmaf(kv, win[e & 0x7FFu], acc);
            }
            acc += __shfl_xor(acc, 1, 64);
            acc += __shfl_xor(acc, 2, 64);
            if (l4 == 0) {
                float Kv  = fmaf(C50, Sw, acc);         // + exp(-50)*sum(w)
                float val = MUV / fmaxf(Kv, EPS_DIVF);
                wout[row] = val;
                psum += val;
            }
        }
        #pragma unroll
        for (int o = 32; o > 0; o >>= 1) psum += __shfl_down(psum, o, 64);
        if (lane == 0) red[ph & 1][wid] = psum;
        __syncthreads();                                // one barrier per phase
    }

    for (int i = tid; i < NPT; i += TPB) {
        gu[base + i] = lu[i];
        gv[base + i] = lv[i];
    }
}

// ================= kernel 3: dense EMD epilogue: sum u*K*v*d ========================
extern "C" __global__ __launch_bounds__(TPB, 2)
void emd_epilogue_56831007261025(const uint8_t* __restrict__ wsb,
                                 float* __restrict__ out)
{
    __shared__ float4 tp[NPT];    // 32 KB
    __shared__ float  lvv[NPT];   //  8 KB
    __shared__ float  red[NWAVE];

    const float4* gspts = (const float4*)(wsb + OFF_SPTS);
    const float4* gtpts = (const float4*)(wsb + OFF_TPTS);
    const float*  gu    = (const float*) (wsb + OFF_U);
    const float*  gv    = (const float*) (wsb + OFF_V);

    const int tid  = threadIdx.x;
    const int lane = tid & 63;
    const int wid  = tid >> 6;
    const int b    = blockIdx.x >> 5;
    const int g    = blockIdx.x & 31;
    const size_t base = (size_t)b * NPT;

    for (int i = tid; i < NPT; i += TPB) {
        tp[i]  = gtpts[base + i];
        lvv[i] = gv[base + i];
    }
    __syncthreads();

    float wacc = 0.0f;
    for (int r = 0; r < 4; ++r) {
        size_t gi = base + g*64 + wid*4 + r;
        float4 sp   = gspts[gi];
        float  uval = gu[gi];
        float racc = 0.0f;
        for (int mb = 0; mb < NPT; mb += 64) {
            int m = mb + lane;
            float4 t = tp[m];
            float dx = sp.x - t.x, dy = sp.y - t.y, dz = sp.z - t.z;
            float d = sqrtf(dx*dx + dy*dy + dz*dz);
            float K = fmaxf(expf(-100.0f * d), C50);    // == exp(-min(100d,50))
            racc = fmaf(K * d, lvv[m], racc);
        }
        #pragma unroll
        for (int o = 32; o > 0; o >>= 1) racc += __shfl_down(racc, o, 64);
        if (lane == 0) wacc = fmaf(uval, racc, wacc);
    }
    if (lane == 0) red[wid] = wacc;
    __syncthreads();
    if (tid == 0) {
        float t = 0.0f;
        #pragma unroll
        for (int w = 0; w < NWAVE; ++w) t += red[w];
        atomicAdd(out, t * 0.125f);                     // mean over 8 batches
    }
}

extern "C" void kernel_launch(void* const* d_in, const int* in_sizes, int n_in,
                              void* d_out, int out_size, void* d_ws, size_t ws_size,
                              hipStream_t stream)
{
    const float* src = (const float*)d_in[0];
    const float* tgt = (const float*)d_in[1];
    float* out = (float*)d_out;
    uint8_t* ws = (uint8_t*)d_ws;

    hipMemsetAsync(out, 0, sizeof(float), stream);

    emd_build_56831007261025<<<dim3(256), dim3(TPB), 0, stream>>>(src, tgt, ws);
    emd_iterate_56831007261025<<<dim3(8), dim3(TPB), 0, stream>>>(ws);
    emd_epilogue_56831007261025<<<dim3(256), dim3(TPB), 0, stream>>>(ws, out);
}

// Round 3
// 1428.247 us; speedup vs baseline: 2.8405x; 2.4514x over previous
//
#include <hip/hip_runtime.h>
#include <stdint.h>
#include <stddef.h>

// ---------------- problem constants ----------------
#define BATCH 8
#define NPT   2048
#define NB    (BATCH*NPT)            // 16384
#define CAP   128                    // max sparse entries per row/col (lambda<=~68, ~7-sigma safe)
#define ITERS 100
#define TPB   1024
#define NWAVE (TPB/64)
#define C50      1.9287498479639178e-22f   // expf(-50.f) == clamp floor of K
#define MUV      (1.0f/2048.0f)
#define EPS_DIVF 1e-8f

// ---------------- workspace layout (bytes), 16B-aligned ----------------
#define OFF_GMAX 0u                                   // 512 u32 (2 KB): [dir][b*32+g]
#define OFF_SPTS 4096u                                // NB*16 = 256 KB
#define OFF_TPTS (OFF_SPTS + (size_t)NB*16)
#define OFF_U    (OFF_TPTS + (size_t)NB*16)
#define OFF_V    (OFF_U + (size_t)NB*4)
#define OFF_ROWE (OFF_V + (size_t)NB*4)               // transposed-ELL slab, 8 MB
#define OFF_COLE (OFF_ROWE + (size_t)NB*CAP*4)        // 8 MB
// total ~16.6 MB

// Pack (K - C50): keep 12 mantissa bits (round-to-nearest), low 11 bits = column index.
__device__ __forceinline__ uint32_t pack_entry(float kv, int idx) {
    uint32_t bb = __float_as_uint(kv);
    bb = (bb + 0x400u) & 0xFFFFF800u;
    return bb | (uint32_t)idx;
}

// ELL-T4 address of entry `ofs` of `row` within a batch slab (dword units):
//   (ofs>>2)*NPT*4 + row*4 + (ofs&3)   -> lane loads dwordx4 at j4*NPT*4 + row*4
__device__ __forceinline__ size_t ellt4_addr(int ofs, int row) {
    return (size_t)(ofs >> 2) * (NPT*4) + (size_t)row * 4 + (ofs & 3);
}

// ================= kernel 1: build transposed-ELL sparse slabs (no atomics) ==========
extern "C" __global__ __launch_bounds__(TPB, 2)
void emd_build_56831007261025(const float* __restrict__ src,
                              const float* __restrict__ tgt,
                              uint8_t* __restrict__ wsb,
                              float* __restrict__ out)
{
    __shared__ float4   opts[NPT];   // 32 KB: scanned cloud
    __shared__ uint32_t cnt_s[64];

    uint32_t* gmax  = (uint32_t*)(wsb + OFF_GMAX);
    float4*   gspts = (float4*)  (wsb + OFF_SPTS);
    float4*   gtpts = (float4*)  (wsb + OFF_TPTS);
    uint32_t* rowE  = (uint32_t*)(wsb + OFF_ROWE);
    uint32_t* colE  = (uint32_t*)(wsb + OFF_COLE);

    const int tid  = threadIdx.x;
    const int lane = tid & 63;
    const int wid  = tid >> 6;
    const int b    = blockIdx.x >> 5;    // batch 0..7
    const int g    = blockIdx.x & 31;    // 64-row group
    const size_t base  = (size_t)b * NPT;
    const size_t ebase = (size_t)b * NPT * CAP;

    if (blockIdx.x == 0 && tid == 0) *out = 0.0f;   // replaces memset dispatch

    // zero-fill this block's 64-row columns in both slabs (padding entries == 0)
    for (int idx = tid; idx < 32*256; idx += TPB) {   // 32 j4-blocks x 256 dwords
        int j4 = idx >> 8, t = idx & 255;
        size_t a = ebase + (size_t)j4*(NPT*4) + (size_t)g*256 + t;
        rowE[a] = 0u;
        colE[a] = 0u;
    }
    // stage float4 point copies for the epilogue
    if (tid < 64) {
        size_t gi = base + g*64 + tid;
        gspts[gi] = make_float4(src[3*gi], src[3*gi+1], src[3*gi+2], 0.0f);
        gtpts[gi] = make_float4(tgt[3*gi], tgt[3*gi+1], tgt[3*gi+2], 0.0f);
    }

    for (int pass = 0; pass < 2; ++pass) {
        const float* mineRaw  = pass ? tgt : src;   // 64 fixed points
        const float* cloudRaw = pass ? src : tgt;   // 2048 scanned points
        uint32_t*    E        = pass ? colE : rowE;

        __syncthreads();
        for (int i = tid; i < NPT; i += TPB) {
            size_t gi = base + i;
            opts[i] = make_float4(cloudRaw[3*gi], cloudRaw[3*gi+1], cloudRaw[3*gi+2], 0.0f);
        }
        __syncthreads();

        for (int r = 0; r < 4; ++r) {
            int n = g*64 + wid*4 + r;               // row within batch
            size_t gi = base + n;
            float4 sp = make_float4(mineRaw[3*gi], mineRaw[3*gi+1], mineRaw[3*gi+2], 0.0f);
            uint32_t cnt = 0;
            for (int mb = 0; mb < NPT; mb += 64) {
                int m = mb + lane;
                float4 tp = opts[m];
                float dx = sp.x - tp.x, dy = sp.y - tp.y, dz = sp.z - tp.z;
                float d2 = dx*dx + dy*dy + dz*dz;
                bool p = d2 < 0.25f;                 // d<0.5 <=> 100d<50; beyond, K==C50 exactly
                uint64_t mask = __ballot(p);
                uint32_t ofs = cnt + (uint32_t)__popcll(mask & ((1ull << lane) - 1ull));
                if (p && ofs < CAP) {
                    float d  = sqrtf(d2);
                    float kv = expf(-100.0f * d) - C50;
                    E[ebase + ellt4_addr((int)ofs, n)] = pack_entry(kv, m);
                }
                cnt += (uint32_t)__popcll(mask);
            }
            if (lane == 0) cnt_s[wid*4 + r] = (cnt < CAP) ? cnt : CAP;
        }
        __syncthreads();
        if (tid == 0) {
            uint32_t mx = 0;
            for (int i = 0; i < 64; ++i) mx = (cnt_s[i] > mx) ? cnt_s[i] : mx;
            gmax[pass*256 + b*32 + g] = mx;
        }
    }
}

// ================= kernel 2: 100 Sinkhorn iterations, one block per batch ============
extern "C" __global__ __launch_bounds__(TPB, 1)
void emd_iterate_56831007261025(uint8_t* __restrict__ wsb)
{
    __shared__ float    lu[NPT];          // 8 KB
    __shared__ float    lv[NPT];          // 8 KB
    __shared__ float    red[2][NWAVE];
    __shared__ uint32_t cflag[NWAVE];
    __shared__ uint32_t gmL[2][32];

    float* gu = (float*)(wsb + OFF_U);
    float* gv = (float*)(wsb + OFF_V);

    const int tid  = threadIdx.x;
    const int lane = tid & 63;
    const int wid  = tid >> 6;
    const int b    = blockIdx.x;
    const size_t ebase = (size_t)b * NPT * CAP;

    const uint32_t* rowE = (const uint32_t*)(wsb + OFF_ROWE) + ebase;
    const uint32_t* colE = (const uint32_t*)(wsb + OFF_COLE) + ebase;
    const uint32_t* gmax = (const uint32_t*)(wsb + OFF_GMAX);

    if (tid < 32) {
        gmL[0][tid] = gmax[b*32 + tid];
        gmL[1][tid] = gmax[256 + b*32 + tid];
    }
    for (int i = tid; i < NPT; i += TPB) lv[i] = 1.0f;   // v0 = ones
    __syncthreads();

    for (int ph = 0; ph < 2*ITERS; ++ph) {
        const bool up = (ph & 1) == 0;                   // u-phase reads v, writes u
        const uint32_t* E    = up ? rowE : colE;
        const float*    win  = up ? lv : lu;
        float*          wout = up ? lu : lv;
        const uint32_t* gm   = gmL[up ? 0 : 1];

        float Sw;
        if (ph == 0) {
            Sw = (float)NPT;                             // sum(v0) = 2048 exactly
        } else {
            float s = 0.0f;
            #pragma unroll
            for (int w = 0; w < NWAVE; ++w) s += red[(ph - 1) & 1][w];
            Sw = s;
        }

        float psum = 0.0f;
        uint32_t chg = 0;
        #pragma unroll
        for (int gsel = 0; gsel < 2; ++gsel) {
            const int grp = wid*2 + gsel;
            const int row = grp*64 + lane;               // 1 lane per row, no divergence
            const int jmax4 = (__builtin_amdgcn_readfirstlane(gm[grp]) + 3) >> 2;
            const uint32_t* ep = E + (size_t)row * 4;
            float acc = 0.0f;
            #pragma unroll 4
            for (int j4 = 0; j4 < jmax4; ++j4) {
                uint4 e4 = *(const uint4*)(ep + (size_t)j4 * (NPT*4));  // coalesced 1 KB/wave
                acc = fmaf(__uint_as_float(e4.x & 0xFFFFF800u), win[e4.x & 0x7FFu], acc);
                acc = fmaf(__uint_as_float(e4.y & 0xFFFFF800u), win[e4.y & 0x7FFu], acc);
                acc = fmaf(__uint_as_float(e4.z & 0xFFFFF800u), win[e4.z & 0x7FFu], acc);
                acc = fmaf(__uint_as_float(e4.w & 0xFFFFF800u), win[e4.w & 0x7FFu], acc);
            }
            float Kv  = fmaf(C50, Sw, acc);              // + exp(-50)*sum(w), exact background
            float val = MUV / fmaxf(Kv, EPS_DIVF);
            if (!up) chg |= (__float_as_uint(val) != __float_as_uint(wout[row]));
            wout[row] = val;
            psum += val;
        }
        #pragma unroll
        for (int o = 32; o > 0; o >>= 1) psum += __shfl_down(psum, o, 64);
        if (lane == 0) red[ph & 1][wid] = psum;
        if (!up) {
            uint64_t m = __ballot(chg != 0);
            if (lane == 0) cflag[wid] = (m != 0ull) ? 1u : 0u;
        }
        __syncthreads();                                 // one barrier per phase
        if (!up) {
            uint32_t any = 0;
            #pragma unroll
            for (int w = 0; w < NWAVE; ++w) any |= cflag[w];
            if (!any) break;   // bitwise fixed point: all remaining iterations identical
        }
    }

    for (int i = tid; i < NPT; i += TPB) {
        gu[(size_t)b*NPT + i] = lu[i];
        gv[(size_t)b*NPT + i] = lv[i];
    }
}

// ================= kernel 3: dense EMD epilogue: sum u*K*v*d ========================
extern "C" __global__ __launch_bounds__(TPB, 2)
void emd_epilogue_56831007261025(const uint8_t* __restrict__ wsb,
                                 float* __restrict__ out)
{
    __shared__ float4 tp[NPT];    // 32 KB
    __shared__ float  lvv[NPT];   //  8 KB
    __shared__ float  red[NWAVE];

    const float4* gspts = (const float4*)(wsb + OFF_SPTS);
    const float4* gtpts = (const float4*)(wsb + OFF_TPTS);
    const float*  gu    = (const float*) (wsb + OFF_U);
    const float*  gv    = (const float*) (wsb + OFF_V);

    const int tid  = threadIdx.x;
    const int lane = tid & 63;
    const int wid  = tid >> 6;
    const int b    = blockIdx.x >> 5;
    const int g    = blockIdx.x & 31;
    const size_t base = (size_t)b * NPT;

    for (int i = tid; i < NPT; i += TPB) {
        tp[i]  = gtpts[base + i];
        lvv[i] = gv[base + i];
    }
    __syncthreads();

    float wacc = 0.0f;
    for (int r = 0; r < 4; ++r) {
        size_t gi = base + g*64 + wid*4 + r;
        float4 sp   = gspts[gi];
        float  uval = gu[gi];
        float racc = 0.0f;
        for (int mb = 0; mb < NPT; mb += 64) {
            int m = mb + lane;
            float4 t = tp[m];
            float dx = sp.x - t.x, dy = sp.y - t.y, dz = sp.z - t.z;
            float d = sqrtf(dx*dx + dy*dy + dz*dz);
            float K = fmaxf(expf(-100.0f * d), C50);    // == exp(-min(100d,50))
            racc = fmaf(K * d, lvv[m], racc);
        }
        #pragma unroll
        for (int o = 32; o > 0; o >>= 1) racc += __shfl_down(racc, o, 64);
        if (lane == 0) wacc = fmaf(uval, racc, wacc);
    }
    if (lane == 0) red[wid] = wacc;
    __syncthreads();
    if (tid == 0) {
        float t = 0.0f;
        #pragma unroll
        for (int w = 0; w < NWAVE; ++w) t += red[w];
        atomicAdd(out, t * 0.125f);                     // mean over 8 batches
    }
}

extern "C" void kernel_launch(void* const* d_in, const int* in_sizes, int n_in,
                              void* d_out, int out_size, void* d_ws, size_t ws_size,
                              hipStream_t stream)
{
    const float* src = (const float*)d_in[0];
    const float* tgt = (const float*)d_in[1];
    float* out = (float*)d_out;
    uint8_t* ws = (uint8_t*)d_ws;

    emd_build_56831007261025<<<dim3(256), dim3(TPB), 0, stream>>>(src, tgt, ws, out);
    emd_iterate_56831007261025<<<dim3(8), dim3(TPB), 0, stream>>>(ws);
    emd_epilogue_56831007261025<<<dim3(256), dim3(TPB), 0, stream>>>(ws, out);
}

// Round 4
// 958.006 us; speedup vs baseline: 4.2348x; 1.4909x over previous
//
#include <hip/hip_runtime.h>
#include <stdint.h>
#include <stddef.h>

// ---------------- problem constants ----------------
#define BATCH 8
#define NPT   2048
#define NB    (BATCH*NPT)            // 16384
#define CAP   128                    // max sparse entries per row/col
#define ITERS 100
#define TPB   1024
#define NWAVE (TPB/64)
#define C50      1.9287498479639178e-22f   // expf(-50.f) == clamp floor of K
#define MUV      (1.0f/2048.0f)
#define EPS_DIVF 1e-8f

// ---------------- workspace layout (bytes), 16B-aligned ----------------
#define OFF_GMAX 0u                                   // gmax[dir][b*32+g], 2 KB used
#define OFF_CNT  4096u                                // cnt[dir][b][n], 128 KB
#define OFF_PERM (OFF_CNT + (size_t)2*NB*4)           // u16 perm[dir][b][p], 64 KB
#define OFF_SPTS (OFF_PERM + (size_t)2*NB*2)          // float4, 256 KB
#define OFF_TPTS (OFF_SPTS + (size_t)NB*16)
#define OFF_U    (OFF_TPTS + (size_t)NB*16)
#define OFF_V    (OFF_U + (size_t)NB*4)
#define OFF_ROWE (OFF_V + (size_t)NB*4)               // ELL-T4 slab (sorted rows), 8 MB
#define OFF_COLE (OFF_ROWE + (size_t)NB*CAP*4)        // 8 MB
// total ~16.8 MB

// Pack (K - C50): keep 12 mantissa bits (round-to-nearest), low 11 bits = column index.
__device__ __forceinline__ uint32_t pack_entry(float kv, int idx) {
    uint32_t bb = __float_as_uint(kv);
    bb = (bb + 0x400u) & 0xFFFFF800u;
    return bb | (uint32_t)idx;
}

// ELL-T4 address of entry `ofs` of sorted-row `p` within a batch slab (dword units)
__device__ __forceinline__ size_t ellt4_addr(int ofs, int p) {
    return (size_t)(ofs >> 2) * (NPT*4) + (size_t)p * 4 + (ofs & 3);
}

// ========== kernel A: stage float4 points + per-row/col entry counts ==========
extern "C" __global__ __launch_bounds__(TPB, 2)
void emd_count_56831007261025(const float* __restrict__ src,
                              const float* __restrict__ tgt,
                              uint8_t* __restrict__ wsb,
                              float* __restrict__ out)
{
    __shared__ float4 opts[NPT];

    uint32_t* cnt   = (uint32_t*)(wsb + OFF_CNT);
    float4*   gspts = (float4*)  (wsb + OFF_SPTS);
    float4*   gtpts = (float4*)  (wsb + OFF_TPTS);

    const int tid  = threadIdx.x;
    const int lane = tid & 63;
    const int wid  = tid >> 6;
    const int b    = blockIdx.x >> 5;
    const int g    = blockIdx.x & 31;
    const size_t base = (size_t)b * NPT;

    if (blockIdx.x == 0 && tid == 0) *out = 0.0f;

    if (tid < 64) {
        size_t gi = base + g*64 + tid;
        gspts[gi] = make_float4(src[3*gi], src[3*gi+1], src[3*gi+2], 0.0f);
        gtpts[gi] = make_float4(tgt[3*gi], tgt[3*gi+1], tgt[3*gi+2], 0.0f);
    }

    for (int pass = 0; pass < 2; ++pass) {
        const float* mineRaw  = pass ? tgt : src;
        const float* cloudRaw = pass ? src : tgt;

        __syncthreads();
        for (int i = tid; i < NPT; i += TPB) {
            size_t gi = base + i;
            opts[i] = make_float4(cloudRaw[3*gi], cloudRaw[3*gi+1], cloudRaw[3*gi+2], 0.0f);
        }
        __syncthreads();

        for (int r = 0; r < 4; ++r) {
            int n = g*64 + wid*4 + r;
            size_t gi = base + n;
            float4 sp = make_float4(mineRaw[3*gi], mineRaw[3*gi+1], mineRaw[3*gi+2], 0.0f);
            uint32_t c = 0;
            for (int mb = 0; mb < NPT; mb += 64) {
                float4 tp = opts[mb + lane];
                float dx = sp.x - tp.x, dy = sp.y - tp.y, dz = sp.z - tp.z;
                float d2 = dx*dx + dy*dy + dz*dz;
                c += (uint32_t)__popcll(__ballot(d2 < 0.25f));
            }
            if (lane == 0) cnt[(size_t)pass*NB + gi] = (c < CAP) ? c : CAP;
        }
    }
}

// ========== kernel B: counting-sort rows by count, per (dir, batch) ==========
extern "C" __global__ __launch_bounds__(256, 4)
void emd_sort_56831007261025(uint8_t* __restrict__ wsb)
{
    __shared__ uint32_t hist[CAP+2];
    __shared__ uint32_t bofs[CAP+2];
    __shared__ uint16_t permL[NPT];

    const int tid = threadIdx.x;
    const int dir = blockIdx.x >> 3;
    const int b   = blockIdx.x & 7;

    const uint32_t* cnt  = (const uint32_t*)(wsb + OFF_CNT) + (size_t)dir*NB + (size_t)b*NPT;
    uint16_t*       perm = (uint16_t*)(wsb + OFF_PERM) + (size_t)dir*NB + (size_t)b*NPT;
    uint32_t*       gmax = (uint32_t*)(wsb + OFF_GMAX) + (size_t)dir*256 + (size_t)b*32;

    for (int i = tid; i < CAP+2; i += 256) hist[i] = 0;
    __syncthreads();
    for (int n = tid; n < NPT; n += 256) atomicAdd(&hist[cnt[n]], 1u);
    __syncthreads();
    if (tid == 0) {
        uint32_t run = 0;
        for (int i = 0; i < CAP+2; ++i) { bofs[i] = run; run += hist[i]; }
    }
    __syncthreads();
    for (int n = tid; n < NPT; n += 256) {
        uint32_t p = atomicAdd(&bofs[cnt[n]], 1u);
        permL[p] = (uint16_t)n;
    }
    __syncthreads();
    for (int p = tid; p < NPT; p += 256) perm[p] = permL[p];
    if (tid < 32) gmax[tid] = cnt[permL[tid*64 + 63]];   // sorted ascending -> group max
}

// ========== kernel C: build ELL-T4 slabs at sorted row positions ==========
extern "C" __global__ __launch_bounds__(TPB, 2)
void emd_build_56831007261025(uint8_t* __restrict__ wsb)
{
    __shared__ float4   opts[NPT];
    __shared__ uint16_t rows[64];

    const float4* gspts = (const float4*)(wsb + OFF_SPTS);
    const float4* gtpts = (const float4*)(wsb + OFF_TPTS);
    uint32_t*     rowE  = (uint32_t*)(wsb + OFF_ROWE);
    uint32_t*     colE  = (uint32_t*)(wsb + OFF_COLE);

    const int tid  = threadIdx.x;
    const int lane = tid & 63;
    const int wid  = tid >> 6;
    const int b    = blockIdx.x >> 5;
    const int g    = blockIdx.x & 31;
    const size_t base  = (size_t)b * NPT;
    const size_t ebase = (size_t)b * NPT * CAP;

    // zero-fill this block's sorted-row slice in both slabs (padding entries == 0)
    for (int idx = tid; idx < 32*256; idx += TPB) {
        int j4 = idx >> 8, t = idx & 255;
        size_t a = ebase + (size_t)j4*(NPT*4) + (size_t)g*256 + t;
        rowE[a] = 0u;
        colE[a] = 0u;
    }

    for (int pass = 0; pass < 2; ++pass) {
        const float4* mine  = pass ? gtpts : gspts;
        const float4* cloud = pass ? gspts : gtpts;
        uint32_t*     E     = pass ? colE : rowE;
        const uint16_t* perm = (const uint16_t*)(wsb + OFF_PERM) + (size_t)pass*NB + base;

        __syncthreads();
        for (int i = tid; i < NPT; i += TPB) opts[i] = cloud[base + i];
        if (tid < 64) rows[tid] = perm[g*64 + tid];
        __syncthreads();

        for (int r = 0; r < 4; ++r) {
            int psort = g*64 + wid*4 + r;              // sorted position (slab row)
            int n     = rows[wid*4 + r];               // original row
            float4 sp = mine[base + n];
            uint32_t c = 0;
            for (int mb = 0; mb < NPT; mb += 64) {
                int m = mb + lane;
                float4 tp = opts[m];
                float dx = sp.x - tp.x, dy = sp.y - tp.y, dz = sp.z - tp.z;
                float d2 = dx*dx + dy*dy + dz*dz;
                bool p = d2 < 0.25f;
                uint64_t mask = __ballot(p);
                uint32_t ofs = c + (uint32_t)__popcll(mask & ((1ull << lane) - 1ull));
                if (p && ofs < CAP) {
                    float d  = sqrtf(d2);
                    float kv = expf(-100.0f * d) - C50;
                    E[ebase + ellt4_addr((int)ofs, psort)] = pack_entry(kv, m);
                }
                c += (uint32_t)__popcll(mask);
            }
        }
    }
}

// ========== kernel D: 100 Sinkhorn iterations, one block per batch ==========
extern "C" __global__ __launch_bounds__(TPB, 1)
void emd_iterate_56831007261025(uint8_t* __restrict__ wsb)
{
    __shared__ float    lu[NPT];          // 8 KB (original row order)
    __shared__ float    lv[NPT];          // 8 KB
    __shared__ uint16_t pm[2][NPT];       // 8 KB: sorted pos -> original row
    __shared__ float    red[2][NWAVE];
    __shared__ uint32_t cflag[NWAVE];
    __shared__ uint32_t gmL[2][32];

    float* gu = (float*)(wsb + OFF_U);
    float* gv = (float*)(wsb + OFF_V);

    const int tid  = threadIdx.x;
    const int lane = tid & 63;
    const int wid  = tid >> 6;
    const int b    = blockIdx.x;
    const size_t ebase = (size_t)b * NPT * CAP;

    const uint32_t* rowE = (const uint32_t*)(wsb + OFF_ROWE) + ebase;
    const uint32_t* colE = (const uint32_t*)(wsb + OFF_COLE) + ebase;
    const uint32_t* gmax = (const uint32_t*)(wsb + OFF_GMAX);
    const uint16_t* prm  = (const uint16_t*)(wsb + OFF_PERM);

    if (tid < 32) {
        gmL[0][tid] = gmax[(size_t)b*32 + tid];
        gmL[1][tid] = gmax[256 + (size_t)b*32 + tid];
    }
    for (int i = tid; i < NPT; i += TPB) {
        pm[0][i] = prm[(size_t)b*NPT + i];
        pm[1][i] = prm[(size_t)NB + (size_t)b*NPT + i];
        lv[i] = 1.0f;                                    // v0 = ones
    }
    __syncthreads();

    for (int ph = 0; ph < 2*ITERS; ++ph) {
        const bool up = (ph & 1) == 0;                   // u-phase reads v, writes u
        const uint32_t* E    = up ? rowE : colE;
        const float*    win  = up ? lv : lu;
        float*          wout = up ? lu : lv;
        const uint32_t* gm   = gmL[up ? 0 : 1];
        const uint16_t* pmd  = pm[up ? 0 : 1];

        float Sw;
        if (ph == 0) {
            Sw = (float)NPT;                             // sum(v0) = 2048 exactly
        } else {
            float s = 0.0f;
            #pragma unroll
            for (int w = 0; w < NWAVE; ++w) s += red[(ph - 1) & 1][w];
            Sw = s;
        }

        float psum = 0.0f;
        uint32_t chg = 0;
        #pragma unroll
        for (int gsel = 0; gsel < 2; ++gsel) {
            const int grp = gsel ? (31 - wid) : wid;     // pair small+large groups per wave
            const int pos = grp*64 + lane;               // sorted row, 1 lane per row
            const int jmax4 = (__builtin_amdgcn_readfirstlane(gm[grp]) + 3) >> 2;
            const uint32_t* ep = E + (size_t)pos * 4;
            float acc = 0.0f;
            #pragma unroll 4
            for (int j4 = 0; j4 < jmax4; ++j4) {
                uint4 e4 = *(const uint4*)(ep + (size_t)j4 * (NPT*4));  // coalesced
                acc = fmaf(__uint_as_float(e4.x & 0xFFFFF800u), win[e4.x & 0x7FFu], acc);
                acc = fmaf(__uint_as_float(e4.y & 0xFFFFF800u), win[e4.y & 0x7FFu], acc);
                acc = fmaf(__uint_as_float(e4.z & 0xFFFFF800u), win[e4.z & 0x7FFu], acc);
                acc = fmaf(__uint_as_float(e4.w & 0xFFFFF800u), win[e4.w & 0x7FFu], acc);
            }
            float Kv  = fmaf(C50, Sw, acc);              // + exp(-50)*sum(w)
            float val = MUV / fmaxf(Kv, EPS_DIVF);
            int orig = pmd[pos];
            if (!up) chg |= (__float_as_uint(val) != __float_as_uint(wout[orig]));
            wout[orig] = val;
            psum += val;
        }
        #pragma unroll
        for (int o = 32; o > 0; o >>= 1) psum += __shfl_down(psum, o, 64);
        if (lane == 0) red[ph & 1][wid] = psum;
        if (!up) {
            uint64_t m = __ballot(chg != 0);
            if (lane == 0) cflag[wid] = (m != 0ull) ? 1u : 0u;
        }
        __syncthreads();
        if (!up) {
            uint32_t any = 0;
            #pragma unroll
            for (int w = 0; w < NWAVE; ++w) any |= cflag[w];
            if (!any) break;   // bitwise fixed point: remaining iterations identical
        }
    }

    for (int i = tid; i < NPT; i += TPB) {
        gu[(size_t)b*NPT + i] = lu[i];
        gv[(size_t)b*NPT + i] = lv[i];
    }
}

// ========== kernel E: dense EMD epilogue: sum u*K*v*d ==========
extern "C" __global__ __launch_bounds__(TPB, 2)
void emd_epilogue_56831007261025(const uint8_t* __restrict__ wsb,
                                 float* __restrict__ out)
{
    __shared__ float4 tp[NPT];
    __shared__ float  lvv[NPT];
    __shared__ float  red[NWAVE];

    const float4* gspts = (const float4*)(wsb + OFF_SPTS);
    const float4* gtpts = (const float4*)(wsb + OFF_TPTS);
    const float*  gu    = (const float*) (wsb + OFF_U);
    const float*  gv    = (const float*) (wsb + OFF_V);

    const int tid  = threadIdx.x;
    const int lane = tid & 63;
    const int wid  = tid >> 6;
    const int b    = blockIdx.x >> 5;
    const int g    = blockIdx.x & 31;
    const size_t base = (size_t)b * NPT;

    for (int i = tid; i < NPT; i += TPB) {
        tp[i]  = gtpts[base + i];
        lvv[i] = gv[base + i];
    }
    __syncthreads();

    float wacc = 0.0f;
    for (int r = 0; r < 4; ++r) {
        size_t gi = base + g*64 + wid*4 + r;
        float4 sp   = gspts[gi];
        float  uval = gu[gi];
        float racc = 0.0f;
        for (int mb = 0; mb < NPT; mb += 64) {
            int m = mb + lane;
            float4 t = tp[m];
            float dx = sp.x - t.x, dy = sp.y - t.y, dz = sp.z - t.z;
            float d = sqrtf(dx*dx + dy*dy + dz*dz);
            float K = fmaxf(expf(-100.0f * d), C50);    // == exp(-min(100d,50))
            racc = fmaf(K * d, lvv[m], racc);
        }
        #pragma unroll
        for (int o = 32; o > 0; o >>= 1) racc += __shfl_down(racc, o, 64);
        if (lane == 0) wacc = fmaf(uval, racc, wacc);
    }
    if (lane == 0) red[wid] = wacc;
    __syncthreads();
    if (tid == 0) {
        float t = 0.0f;
        #pragma unroll
        for (int w = 0; w < NWAVE; ++w) t += red[w];
        atomicAdd(out, t * 0.125f);                     // mean over 8 batches
    }
}

extern "C" void kernel_launch(void* const* d_in, const int* in_sizes, int n_in,
                              void* d_out, int out_size, void* d_ws, size_t ws_size,
                              hipStream_t stream)
{
    const float* src = (const float*)d_in[0];
    const float* tgt = (const float*)d_in[1];
    float* out = (float*)d_out;
    uint8_t* ws = (uint8_t*)d_ws;

    emd_count_56831007261025  <<<dim3(256), dim3(TPB), 0, stream>>>(src, tgt, ws, out);
    emd_sort_56831007261025   <<<dim3(16),  dim3(256), 0, stream>>>(ws);
    emd_build_56831007261025  <<<dim3(256), dim3(TPB), 0, stream>>>(ws);
    emd_iterate_56831007261025<<<dim3(8),   dim3(TPB), 0, stream>>>(ws);
    emd_epilogue_56831007261025<<<dim3(256), dim3(TPB), 0, stream>>>(ws, out);
}